// Round 2
// baseline (191.122 us; speedup 1.0000x reference)
//
#include <hip/hip_runtime.h>
#include <hip/hip_bf16.h>
#include <math.h>

#define N_Q   512
#define M_ALL 2048
#define CHN   256
#define TOPK  6
#define BLOCK 256
#define WAVES (BLOCK / 64)
#define MPT   (M_ALL / BLOCK)   // 8 m-rows per thread
#define NCAND (WAVES * TOPK)    // 24 cross-wave candidates

__global__ __launch_bounds__(BLOCK) void gcn_main(
    const float* __restrict__ micro,      // [N,C]
    const float* __restrict__ label,      // [N]
    const float* __restrict__ micro_all,  // [M,C]
    const float* __restrict__ label_all,  // [M]
    const float* __restrict__ fc_w,       // [C]
    float* __restrict__ out,              // [N*C + 1]
    float* __restrict__ loss_accum)       // [1], pre-zeroed
{
    __shared__ float s_micro[CHN];
    __shared__ float s_w[CHN];
    __shared__ float s_cv[NCAND];
    __shared__ int   s_ci[NCAND];

    const int n    = blockIdx.x;
    const int t    = threadIdx.x;
    const int wave = t >> 6;
    const int lane = t & 63;

    // Stage query row + effective weight (fc_w - 1/C) in LDS
    s_micro[t] = micro[n * CHN + t];
    s_w[t]     = fc_w[t] - (1.0f / (float)CHN);
    __syncthreads();

    // ---- Phase 1: logits.  anti[n,m] = sum_c (b-a)^2 * w[c]  (row const dropped implicitly is fine; full form kept) ----
    float logit[MPT];
    for (int j = 0; j < MPT; ++j) {
        const int m = t + j * BLOCK;
        const float4* row = (const float4*)(micro_all + (size_t)m * CHN);
        float acc = 0.0f;
        #pragma unroll 8
        for (int c4 = 0; c4 < CHN / 4; ++c4) {
            float4 a = row[c4];
            const int c = c4 * 4;
            float d0 = a.x - s_micro[c + 0];
            float d1 = a.y - s_micro[c + 1];
            float d2 = a.z - s_micro[c + 2];
            float d3 = a.w - s_micro[c + 3];
            acc += d0 * d0 * s_w[c + 0];
            acc += d1 * d1 * s_w[c + 1];
            acc += d2 * d2 * s_w[c + 2];
            acc += d3 * d3 * s_w[c + 3];
        }
        logit[j] = acc;
    }

    // ---- Phase 2a: per-wave iterative top-6 via shfl_xor butterflies (no barriers) ----
    unsigned taken = 0u;   // exclusion over this thread's MPT slots
    float wv[TOPK];
    int   wi[TOPK];
    #pragma unroll
    for (int k = 0; k < TOPK; ++k) {
        float best  = -INFINITY;
        int   bestj = -1;
        #pragma unroll
        for (int j = 0; j < MPT; ++j) {
            bool avail = ((taken >> j) & 1u) == 0u;
            if (avail && logit[j] > best) { best = logit[j]; bestj = j; }
        }
        float v  = best;
        int   mi = (bestj < 0) ? -1 : (t + bestj * BLOCK);
        #pragma unroll
        for (int mask = 32; mask > 0; mask >>= 1) {
            float ov = __shfl_xor(v,  mask, 64);
            int   om = __shfl_xor(mi, mask, 64);
            if (ov > v) { v = ov; mi = om; }
        }
        wv[k] = v;
        wi[k] = mi;
        // owner thread of mi marks its slot taken:  m = t + j*BLOCK
        if (mi >= 0 && t == (mi & (BLOCK - 1))) taken |= 1u << (mi >> 8);
    }
    if (lane == 0) {
        #pragma unroll
        for (int k = 0; k < TOPK; ++k) {
            s_cv[wave * TOPK + k] = wv[k];
            s_ci[wave * TOPK + k] = wi[k];
        }
    }
    __syncthreads();

    // ---- Phase 2b: every thread selects final top-6 from the 24 candidates ----
    float top_val[TOPK];
    int   top_idx[TOPK];
    unsigned ctk = 0u;
    #pragma unroll
    for (int k = 0; k < TOPK; ++k) {
        float best = -INFINITY;
        int   bi   = 0;
        #pragma unroll
        for (int c = 0; c < NCAND; ++c) {
            bool avail = ((ctk >> c) & 1u) == 0u;
            float cv = s_cv[c];
            if (avail && cv > best) { best = cv; bi = c; }
        }
        top_val[k] = best;
        top_idx[k] = s_ci[bi];
        ctk |= 1u << bi;
    }

    // ---- Phase 3: softmax over the 6 selected logits ----
    const float mx = top_val[0];     // first argmax is the global max
    float e[TOPK];
    float esum = 0.0f;
    #pragma unroll
    for (int k = 0; k < TOPK; ++k) { e[k] = __expf(top_val[k] - mx); esum += e[k]; }
    const float inv = 1.0f / esum;

    // ---- Phase 4: epilogue ----
    float outv = s_micro[t];
    #pragma unroll
    for (int k = 0; k < TOPK; ++k) {
        outv += (e[k] * inv) * micro_all[(size_t)top_idx[k] * CHN + t];
    }
    out[n * CHN + t] = outv;

    if (t == 0) {
        const float lab = label[n];
        float l = 0.0f;
        #pragma unroll
        for (int k = 0; k < TOPK; ++k) {
            l += (e[k] * inv) * fabsf(label_all[top_idx[k]] - lab);
        }
        atomicAdd(loss_accum, l);
    }
}

__global__ void gcn_finalize(const float* __restrict__ loss_accum,
                             float* __restrict__ out)
{
    out[N_Q * CHN] = 1e-4f + loss_accum[0] / (float)N_Q;
}

extern "C" void kernel_launch(void* const* d_in, const int* in_sizes, int n_in,
                              void* d_out, int out_size, void* d_ws, size_t ws_size,
                              hipStream_t stream) {
    const float* micro     = (const float*)d_in[0];
    const float* label     = (const float*)d_in[1];
    const float* micro_all = (const float*)d_in[2];
    const float* label_all = (const float*)d_in[3];
    const float* fc_w      = (const float*)d_in[4];
    float* out        = (float*)d_out;
    float* loss_accum = (float*)d_ws;

    hipMemsetAsync(loss_accum, 0, sizeof(float), stream);
    gcn_main<<<N_Q, BLOCK, 0, stream>>>(micro, label, micro_all, label_all,
                                        fc_w, out, loss_accum);
    gcn_finalize<<<1, 1, 0, stream>>>(loss_accum, out);
}

// Round 3
// 143.191 us; speedup vs baseline: 1.3347x; 1.3347x over previous
//
#include <hip/hip_runtime.h>
#include <hip/hip_bf16.h>
#include <math.h>

#define N_Q   512
#define M_ALL 2048
#define CHN   256
#define TOPK  6
#define BLOCK 256
#define WAVES (BLOCK / 64)
#define MPT   (M_ALL / BLOCK)     // 8 logits per thread for top-k
#define NCAND (WAVES * TOPK)      // 24 cross-wave candidates
#define ROWS_PER_WAVE (M_ALL / WAVES)   // 512
#define ITERS (ROWS_PER_WAVE / 4)       // 128 (4 rows per wave-iter)

__global__ __launch_bounds__(BLOCK) void gcn_main(
    const float* __restrict__ micro,      // [N,C]
    const float* __restrict__ label,      // [N]
    const float* __restrict__ micro_all,  // [M,C]
    const float* __restrict__ label_all,  // [M]
    const float* __restrict__ fc_w,       // [C]
    float* __restrict__ out,              // [N*C + 1]
    float* __restrict__ loss_accum)       // [1], pre-zeroed
{
    __shared__ float s_micro[CHN];
    __shared__ float s_w[CHN];
    __shared__ float s_logit[M_ALL];      // 8 KB
    __shared__ float s_cv[NCAND];
    __shared__ int   s_ci[NCAND];

    const int n    = blockIdx.x;
    const int t    = threadIdx.x;
    const int wave = t >> 6;
    const int lane = t & 63;
    const int g    = lane >> 4;   // quarter-group 0..3 (row within 4-row pack)
    const int s    = lane & 15;   // sub-lane within group

    s_micro[t] = micro[n * CHN + t];
    s_w[t]     = fc_w[t] - (1.0f / (float)CHN);
    __syncthreads();

    // Hoist this lane's channel slice of micro/w: channels are lane-fixed
    // (c4 = ph*16 + s), identical for every row -> 8 float4 registers.
    float4 mu[4], ww[4];
    #pragma unroll
    for (int ph = 0; ph < 4; ++ph) {
        const int c4 = ph * 16 + s;
        mu[ph] = ((const float4*)s_micro)[c4];
        ww[ph] = ((const float4*)s_w)[c4];
    }

    // ---- Phase 1: logits, wave-cooperative coalesced reads ----
    // wave w owns rows [w*512, w*512+512), 4 rows per iteration (one per group).
    const int row0 = wave * ROWS_PER_WAVE;
    #pragma unroll 2
    for (int it = 0; it < ITERS; ++it) {
        const int row = row0 + (it << 2) + g;
        const float4* rp = (const float4*)(micro_all + (size_t)row * CHN);
        float acc = 0.0f;
        #pragma unroll
        for (int ph = 0; ph < 4; ++ph) {
            const float4 a = rp[ph * 16 + s];   // 16 lanes x 16B contiguous
            float d0 = a.x - mu[ph].x;
            float d1 = a.y - mu[ph].y;
            float d2 = a.z - mu[ph].z;
            float d3 = a.w - mu[ph].w;
            acc += d0 * d0 * ww[ph].x;
            acc += d1 * d1 * ww[ph].y;
            acc += d2 * d2 * ww[ph].z;
            acc += d3 * d3 * ww[ph].w;
        }
        // 16-lane butterfly sum (stays within the quarter-group)
        #pragma unroll
        for (int mask = 8; mask >= 1; mask >>= 1)
            acc += __shfl_xor(acc, mask, 64);
        if (s == 0) s_logit[row] = acc;
    }
    __syncthreads();

    // Reload logits in top-k ownership layout: thread t owns rows t + j*256
    float logit[MPT];
    #pragma unroll
    for (int j = 0; j < MPT; ++j) logit[j] = s_logit[t + j * BLOCK];

    // ---- Phase 2a: per-wave iterative top-6 via shfl_xor butterflies ----
    unsigned taken = 0u;
    float wv[TOPK];
    int   wi[TOPK];
    #pragma unroll
    for (int k = 0; k < TOPK; ++k) {
        float best  = -INFINITY;
        int   bestj = -1;
        #pragma unroll
        for (int j = 0; j < MPT; ++j) {
            bool avail = ((taken >> j) & 1u) == 0u;
            if (avail && logit[j] > best) { best = logit[j]; bestj = j; }
        }
        float v  = best;
        int   mi = (bestj < 0) ? -1 : (t + bestj * BLOCK);
        #pragma unroll
        for (int mask = 32; mask > 0; mask >>= 1) {
            float ov = __shfl_xor(v,  mask, 64);
            int   om = __shfl_xor(mi, mask, 64);
            if (ov > v) { v = ov; mi = om; }
        }
        wv[k] = v;
        wi[k] = mi;
        if (mi >= 0 && t == (mi & (BLOCK - 1))) taken |= 1u << (mi >> 8);
    }
    if (lane == 0) {
        #pragma unroll
        for (int k = 0; k < TOPK; ++k) {
            s_cv[wave * TOPK + k] = wv[k];
            s_ci[wave * TOPK + k] = wi[k];
        }
    }
    __syncthreads();

    // ---- Phase 2b: final top-6 from 24 candidates (every thread, sync-free) ----
    float top_val[TOPK];
    int   top_idx[TOPK];
    unsigned ctk = 0u;
    #pragma unroll
    for (int k = 0; k < TOPK; ++k) {
        float best = -INFINITY;
        int   bi   = 0;
        #pragma unroll
        for (int c = 0; c < NCAND; ++c) {
            bool avail = ((ctk >> c) & 1u) == 0u;
            float cv = s_cv[c];
            if (avail && cv > best) { best = cv; bi = c; }
        }
        top_val[k] = best;
        top_idx[k] = s_ci[bi];
        ctk |= 1u << bi;
    }

    // ---- Phase 3: softmax over the 6 selected logits ----
    const float mx = top_val[0];
    float e[TOPK];
    float esum = 0.0f;
    #pragma unroll
    for (int k = 0; k < TOPK; ++k) { e[k] = __expf(top_val[k] - mx); esum += e[k]; }
    const float inv = 1.0f / esum;

    // ---- Phase 4: epilogue ----
    float outv = s_micro[t];
    #pragma unroll
    for (int k = 0; k < TOPK; ++k) {
        outv += (e[k] * inv) * micro_all[(size_t)top_idx[k] * CHN + t];
    }
    out[n * CHN + t] = outv;

    if (t == 0) {
        const float lab = label[n];
        float l = 0.0f;
        #pragma unroll
        for (int k = 0; k < TOPK; ++k) {
            l += (e[k] * inv) * fabsf(label_all[top_idx[k]] - lab);
        }
        atomicAdd(loss_accum, l);
    }
}

__global__ void gcn_finalize(const float* __restrict__ loss_accum,
                             float* __restrict__ out)
{
    out[N_Q * CHN] = 1e-4f + loss_accum[0] / (float)N_Q;
}

extern "C" void kernel_launch(void* const* d_in, const int* in_sizes, int n_in,
                              void* d_out, int out_size, void* d_ws, size_t ws_size,
                              hipStream_t stream) {
    const float* micro     = (const float*)d_in[0];
    const float* label     = (const float*)d_in[1];
    const float* micro_all = (const float*)d_in[2];
    const float* label_all = (const float*)d_in[3];
    const float* fc_w      = (const float*)d_in[4];
    float* out        = (float*)d_out;
    float* loss_accum = (float*)d_ws;

    hipMemsetAsync(loss_accum, 0, sizeof(float), stream);
    gcn_main<<<N_Q, BLOCK, 0, stream>>>(micro, label, micro_all, label_all,
                                        fc_w, out, loss_accum);
    gcn_finalize<<<1, 1, 0, stream>>>(loss_accum, out);
}

// Round 4
// 105.355 us; speedup vs baseline: 1.8141x; 1.3591x over previous
//
#include <hip/hip_runtime.h>
#include <hip/hip_bf16.h>
#include <math.h>

#define N_Q   512
#define M_ALL 2048
#define CHN   256
#define TOPK  6
#define INV_C (1.0f / 256.0f)

// ---- workspace layout (float offsets) ----
#define WS_LOSS  0      // [1]
#define WS_BIAS  256    // [M_ALL]
#define WS_LOGIT 4096   // [N_Q][M_ALL]  (n-major)

// =============== kernel 1: bias[m] = sum_c w~_c * a_mc^2 ===============
__global__ __launch_bounds__(256) void gcn_bias(
    const float* __restrict__ micro_all,
    const float* __restrict__ fc_w,
    float* __restrict__ bias)
{
    const int t    = threadIdx.x;
    const int lane = t & 63;
    const int wave = t >> 6;
    float4 w4 = *(const float4*)(fc_w + lane * 4);
    w4.x -= INV_C; w4.y -= INV_C; w4.z -= INV_C; w4.w -= INV_C;
    const int row0 = blockIdx.x * 32 + wave * 8;
    #pragma unroll
    for (int i = 0; i < 8; ++i) {
        const int row = row0 + i;
        float4 a = *(const float4*)(micro_all + (size_t)row * CHN + lane * 4);
        float acc = a.x * a.x * w4.x + a.y * a.y * w4.y
                  + a.z * a.z * w4.z + a.w * a.w * w4.w;
        #pragma unroll
        for (int mask = 32; mask >= 1; mask >>= 1)
            acc += __shfl_xor(acc, mask, 64);
        if (lane == 0) bias[row] = acc;
    }
}

// =============== kernel 2: logits[n][m] = bias[m] - 2*sum_c (w~_c a_mc) b_nc ===============
#define BM 64
#define BN 32
#define KC 64
#define LDA (BM + 4)   // 68 floats -> 272B rows (16B aligned)
#define LDB (BN + 4)   // 36 floats -> 144B rows (8B aligned)

__global__ __launch_bounds__(256) void gcn_gemm(
    const float* __restrict__ micro_all,  // A [M, C]
    const float* __restrict__ micro,      // B [N, C]
    const float* __restrict__ fc_w,
    const float* __restrict__ bias,
    float* __restrict__ logits)           // [N_Q][M_ALL]
{
    __shared__ float As[KC][LDA];
    __shared__ float Bs[KC][LDB];
    __shared__ float s_w[CHN];

    const int t  = threadIdx.x;
    const int m0 = blockIdx.x * BM;
    const int n0 = blockIdx.y * BN;
    const int tm = t & 15;    // 16 groups of 4 m
    const int tn = t >> 4;    // 16 groups of 2 n

    s_w[t] = fc_w[t] - INV_C;
    __syncthreads();

    float acc00 = 0.f, acc01 = 0.f, acc10 = 0.f, acc11 = 0.f;
    float acc20 = 0.f, acc21 = 0.f, acc30 = 0.f, acc31 = 0.f;

    for (int kc0 = 0; kc0 < CHN; kc0 += KC) {
        // stage A-tile (64 rows x 64 c), scaled by w~, transposed to [c][m]
        #pragma unroll
        for (int i = 0; i < 4; ++i) {
            const int item = t + i * 256;
            const int r = item >> 4, c4 = item & 15;
            float4 v = *(const float4*)(micro_all + (size_t)(m0 + r) * CHN + kc0 + c4 * 4);
            As[c4 * 4 + 0][r] = v.x * s_w[kc0 + c4 * 4 + 0];
            As[c4 * 4 + 1][r] = v.y * s_w[kc0 + c4 * 4 + 1];
            As[c4 * 4 + 2][r] = v.z * s_w[kc0 + c4 * 4 + 2];
            As[c4 * 4 + 3][r] = v.w * s_w[kc0 + c4 * 4 + 3];
        }
        // stage B-tile (32 rows x 64 c), transposed to [c][n]
        #pragma unroll
        for (int i = 0; i < 2; ++i) {
            const int item = t + i * 256;
            const int r = item >> 4, c4 = item & 15;
            float4 v = *(const float4*)(micro + (size_t)(n0 + r) * CHN + kc0 + c4 * 4);
            Bs[c4 * 4 + 0][r] = v.x;
            Bs[c4 * 4 + 1][r] = v.y;
            Bs[c4 * 4 + 2][r] = v.z;
            Bs[c4 * 4 + 3][r] = v.w;
        }
        __syncthreads();

        #pragma unroll 16
        for (int k = 0; k < KC; ++k) {
            const float4 a = *(const float4*)&As[k][tm * 4];
            const float2 b = *(const float2*)&Bs[k][tn * 2];
            acc00 += a.x * b.x; acc01 += a.x * b.y;
            acc10 += a.y * b.x; acc11 += a.y * b.y;
            acc20 += a.z * b.x; acc21 += a.z * b.y;
            acc30 += a.w * b.x; acc31 += a.w * b.y;
        }
        __syncthreads();
    }

    // epilogue: logit = bias[m] - 2*acc, write [n][m] (coalesced float4 over tm)
    const float4 bi = *(const float4*)(bias + m0 + tm * 4);
    {
        const int n = n0 + tn * 2;
        float4 o;
        o.x = bi.x - 2.f * acc00;
        o.y = bi.y - 2.f * acc10;
        o.z = bi.z - 2.f * acc20;
        o.w = bi.w - 2.f * acc30;
        *(float4*)&logits[(size_t)n * M_ALL + m0 + tm * 4] = o;
    }
    {
        const int n = n0 + tn * 2 + 1;
        float4 o;
        o.x = bi.x - 2.f * acc01;
        o.y = bi.y - 2.f * acc11;
        o.z = bi.z - 2.f * acc21;
        o.w = bi.w - 2.f * acc31;
        *(float4*)&logits[(size_t)n * M_ALL + m0 + tm * 4] = o;
    }
}

// =============== kernel 3: top-6 + softmax + epilogue ===============
#define BLOCK 256
#define WAVES (BLOCK / 64)
#define MPT   (M_ALL / BLOCK)
#define NCAND (WAVES * TOPK)

__global__ __launch_bounds__(BLOCK) void gcn_topk(
    const float* __restrict__ logits,     // [N_Q][M_ALL]
    const float* __restrict__ micro,      // [N,C]
    const float* __restrict__ label,      // [N]
    const float* __restrict__ micro_all,  // [M,C]
    const float* __restrict__ label_all,  // [M]
    float* __restrict__ out,              // [N*C + 1]
    float* __restrict__ loss_accum)
{
    __shared__ float s_cv[NCAND];
    __shared__ int   s_ci[NCAND];

    const int n    = blockIdx.x;
    const int t    = threadIdx.x;
    const int wave = t >> 6;
    const int lane = t & 63;

    float logit[MPT];
    #pragma unroll
    for (int j = 0; j < MPT; ++j)
        logit[j] = logits[(size_t)n * M_ALL + t + j * BLOCK];

    // per-wave iterative top-6 via shfl_xor butterflies
    unsigned taken = 0u;
    float wv[TOPK];
    int   wi[TOPK];
    #pragma unroll
    for (int k = 0; k < TOPK; ++k) {
        float best  = -INFINITY;
        int   bestj = -1;
        #pragma unroll
        for (int j = 0; j < MPT; ++j) {
            bool avail = ((taken >> j) & 1u) == 0u;
            if (avail && logit[j] > best) { best = logit[j]; bestj = j; }
        }
        float v  = best;
        int   mi = (bestj < 0) ? -1 : (t + bestj * BLOCK);
        #pragma unroll
        for (int mask = 32; mask > 0; mask >>= 1) {
            float ov = __shfl_xor(v,  mask, 64);
            int   om = __shfl_xor(mi, mask, 64);
            if (ov > v) { v = ov; mi = om; }
        }
        wv[k] = v;
        wi[k] = mi;
        if (mi >= 0 && t == (mi & (BLOCK - 1))) taken |= 1u << (mi >> 8);
    }
    if (lane == 0) {
        #pragma unroll
        for (int k = 0; k < TOPK; ++k) {
            s_cv[wave * TOPK + k] = wv[k];
            s_ci[wave * TOPK + k] = wi[k];
        }
    }
    __syncthreads();

    // final top-6 from 24 candidates (redundant per thread, sync-free)
    float top_val[TOPK];
    int   top_idx[TOPK];
    unsigned ctk = 0u;
    #pragma unroll
    for (int k = 0; k < TOPK; ++k) {
        float best = -INFINITY;
        int   bi   = 0;
        #pragma unroll
        for (int c = 0; c < NCAND; ++c) {
            bool avail = ((ctk >> c) & 1u) == 0u;
            float cv = s_cv[c];
            if (avail && cv > best) { best = cv; bi = c; }
        }
        top_val[k] = best;
        top_idx[k] = s_ci[bi];
        ctk |= 1u << bi;
    }

    // softmax over selected logits (full-softmax denom cancels in renorm)
    const float mx = top_val[0];
    float e[TOPK];
    float esum = 0.0f;
    #pragma unroll
    for (int k = 0; k < TOPK; ++k) { e[k] = __expf(top_val[k] - mx); esum += e[k]; }
    const float inv = 1.0f / esum;

    float outv = micro[(size_t)n * CHN + t];
    #pragma unroll
    for (int k = 0; k < TOPK; ++k)
        outv += (e[k] * inv) * micro_all[(size_t)top_idx[k] * CHN + t];
    out[n * CHN + t] = outv;

    if (t == 0) {
        const float lab = label[n];
        float l = 0.0f;
        #pragma unroll
        for (int k = 0; k < TOPK; ++k)
            l += (e[k] * inv) * fabsf(label_all[top_idx[k]] - lab);
        atomicAdd(loss_accum, l);
    }
}

__global__ void gcn_finalize(const float* __restrict__ loss_accum,
                             float* __restrict__ out)
{
    out[N_Q * CHN] = 1e-4f + loss_accum[0] / (float)N_Q;
}

extern "C" void kernel_launch(void* const* d_in, const int* in_sizes, int n_in,
                              void* d_out, int out_size, void* d_ws, size_t ws_size,
                              hipStream_t stream) {
    const float* micro     = (const float*)d_in[0];
    const float* label     = (const float*)d_in[1];
    const float* micro_all = (const float*)d_in[2];
    const float* label_all = (const float*)d_in[3];
    const float* fc_w      = (const float*)d_in[4];
    float* out  = (float*)d_out;
    float* ws   = (float*)d_ws;
    float* loss   = ws + WS_LOSS;
    float* bias   = ws + WS_BIAS;
    float* logits = ws + WS_LOGIT;

    hipMemsetAsync(loss, 0, sizeof(float), stream);
    gcn_bias<<<M_ALL / 32, 256, 0, stream>>>(micro_all, fc_w, bias);
    gcn_gemm<<<dim3(M_ALL / BM, N_Q / BN), 256, 0, stream>>>(micro_all, micro,
                                                             fc_w, bias, logits);
    gcn_topk<<<N_Q, BLOCK, 0, stream>>>(logits, micro, label, micro_all,
                                        label_all, out, loss);
    gcn_finalize<<<1, 1, 0, stream>>>(loss, out);
}